// Round 8
// baseline (170.905 us; speedup 1.0000x reference)
//
#include <hip/hip_runtime.h>
#include <math.h>

#define EMB 512
#define NH 8
#define HD 64
#define BB 2
#define SS 1024
#define ROWS (BB * SS) /* 2048 */

typedef __attribute__((ext_vector_type(8))) short bhalf8;
typedef __attribute__((ext_vector_type(4))) float f32x4;
typedef __attribute__((ext_vector_type(8))) unsigned short us8;
typedef unsigned short ushort_t;

__device__ __forceinline__ unsigned short f2bf(float x) {
  unsigned u = __float_as_uint(x);
  u = (u + 0x7FFFu + ((u >> 16) & 1u)) >> 16;
  return (unsigned short)u;
}
__device__ __forceinline__ float bf2f(unsigned short v) {
  return __uint_as_float(((unsigned)v) << 16);
}
__device__ __forceinline__ float fast_tanh(float x) {
  x = fminf(15.f, fmaxf(-15.f, x));
  const float e = __expf(2.f * x);
  return (e - 1.f) / (e + 1.f);
}

// ============================================================
// proj+pe MFMA GEMM (unchanged from round 7).
// ============================================================
__global__ __launch_bounds__(256, 3) void projpe_kernel(
    const float* __restrict__ f_emb, const float* __restrict__ gpe,
    const float* __restrict__ Wu, const float* __restrict__ Wq,
    const float* __restrict__ Wkv, const float* __restrict__ Wp,
    const float* __restrict__ Wu_b, const float* __restrict__ Wq_b,
    const float* __restrict__ Wkv_b, const float* __restrict__ Wp_b,
    const float* __restrict__ Buc, const float* __restrict__ Bup,
    const float* __restrict__ Bfc, const float* __restrict__ Bfp,
    ushort_t* __restrict__ Qcomb, ushort_t* __restrict__ Kcomb,
    ushort_t* __restrict__ vhT) {
  const int bx = blockIdx.x;
  const int mb = blockIdx.y * 128;
  const int tid = threadIdx.x;
  const int w = tid >> 6, lane = tid & 63;
  const int ln = lane & 15, quad = lane >> 4;
  const int wm = (w >> 1) * 64, wn = (w & 1) * 32;

  __shared__ __align__(16) ushort_t sA[128 * 72];
  __shared__ __align__(16) ushort_t sB[64 * 72];

  if (bx == 0 && blockIdx.y == 0) {
    const int t2 = tid >> 7, rem = tid & 127;
    const int h = rem >> 4, d4 = (rem & 15) * 4;
    *(ushort4*)&Qcomb[((size_t)t2 * ROWS + 1023) * 1024 + h * 128 + 64 + d4] =
        make_ushort4(0, 0, 0, 0);
  }

  const bool isPe = (bx >= 32);
  const int nb = isPe ? 0 : bx * 64;
  const int npbase = isPe ? (bx - 32) * 64 : 0;
  const float* Af = isPe ? gpe : f_emb;
  const int lda = isPe ? 128 : 512;
  const int trips = isPe ? 2 : 8;

  const float* Wsrc;
  int Nw, coff;
  if (isPe) { Wsrc = Wp; Nw = 512; coff = npbase; }
  else if (nb < 512) { Wsrc = Wu; Nw = 512; coff = nb; }
  else if (nb < 1024) { Wsrc = Wq; Nw = 512; coff = nb - 512; }
  else { Wsrc = Wkv; Nw = 1024; coff = nb - 1024; }

  const int bn = tid & 63;
  const int bk0 = (tid >> 6) * 16;

  f32x4 acc[4][2];
#pragma unroll
  for (int rt = 0; rt < 4; ++rt)
#pragma unroll
    for (int ct = 0; ct < 2; ++ct) acc[rt][ct] = (f32x4){0.f, 0.f, 0.f, 0.f};

  float4 qa[8];
  float qbw[16];
#pragma unroll
  for (int i = 0; i < 4; ++i) {
    const int idx = tid + i * 256;
    const size_t base = (size_t)(mb + (idx >> 3)) * lda + (idx & 7) * 8;
    qa[2 * i] = *(const float4*)&Af[base];
    qa[2 * i + 1] = *(const float4*)&Af[base + 4];
  }
#pragma unroll
  for (int j = 0; j < 16; ++j)
    qbw[j] = Wsrc[(size_t)(bk0 + j) * Nw + coff + bn];

  for (int t0 = 0; t0 < trips; ++t0) {
    __syncthreads();
#pragma unroll
    for (int i = 0; i < 4; ++i) {
      const int idx = tid + i * 256;
      us8 o;
      const float4 a = qa[2 * i], b = qa[2 * i + 1];
      o[0] = f2bf(a.x); o[1] = f2bf(a.y); o[2] = f2bf(a.z); o[3] = f2bf(a.w);
      o[4] = f2bf(b.x); o[5] = f2bf(b.y); o[6] = f2bf(b.z); o[7] = f2bf(b.w);
      *(us8*)&sA[(idx >> 3) * 72 + (idx & 7) * 8] = o;
    }
    {
      us8 o0, o1;
#pragma unroll
      for (int j = 0; j < 8; ++j) {
        o0[j] = f2bf(qbw[j]);
        o1[j] = f2bf(qbw[8 + j]);
      }
      *(us8*)&sB[bn * 72 + bk0] = o0;
      *(us8*)&sB[bn * 72 + bk0 + 8] = o1;
    }
    __syncthreads();
    if (t0 < trips - 1) {
      const int k1 = (t0 + 1) * 64;
#pragma unroll
      for (int i = 0; i < 4; ++i) {
        const int idx = tid + i * 256;
        const size_t base = (size_t)(mb + (idx >> 3)) * lda + k1 + (idx & 7) * 8;
        qa[2 * i] = *(const float4*)&Af[base];
        qa[2 * i + 1] = *(const float4*)&Af[base + 4];
      }
#pragma unroll
      for (int j = 0; j < 16; ++j)
        qbw[j] = Wsrc[(size_t)(k1 + bk0 + j) * Nw + coff + bn];
    }
#pragma unroll
    for (int kc = 0; kc < 2; ++kc) {
      bhalf8 af[4], bf_[2];
#pragma unroll
      for (int rt = 0; rt < 4; ++rt)
        af[rt] =
            *(const bhalf8*)&sA[(wm + rt * 16 + ln) * 72 + kc * 32 + quad * 8];
#pragma unroll
      for (int ct = 0; ct < 2; ++ct)
        bf_[ct] =
            *(const bhalf8*)&sB[(wn + ct * 16 + ln) * 72 + kc * 32 + quad * 8];
#pragma unroll
      for (int rt = 0; rt < 4; ++rt)
#pragma unroll
        for (int ct = 0; ct < 2; ++ct)
          acc[rt][ct] = __builtin_amdgcn_mfma_f32_16x16x32_bf16(
              af[rt], bf_[ct], acc[rt][ct], 0, 0, 0);
    }
  }

  __syncthreads();
  ushort_t* sOut = sA;

  if (!isPe && nb >= 1536) {
#pragma unroll
    for (int ct = 0; ct < 2; ++ct) {
      const int nl = wn + ct * 16 + ln;
      const float wb = Wkv_b[nb + nl - 1024];
#pragma unroll
      for (int rt = 0; rt < 4; ++rt)
#pragma unroll
        for (int r = 0; r < 4; ++r) {
          const int ml = wm + rt * 16 + quad * 4 + r;
          sOut[nl * 136 + ml] = f2bf(fast_tanh(acc[rt][ct][r] + wb));
        }
    }
    __syncthreads();
    const int b = mb >> 10, mo = mb & 1023;
#pragma unroll
    for (int i = 0; i < 4; ++i) {
      const int idx = tid + i * 256;
      const int nl = idx >> 4, m8 = (idx & 15) * 8;
      const us8 v = *(const us8*)&sOut[nl * 136 + m8];
      *(us8*)&vhT[((size_t)b * 512 + (nb - 1536) + nl) * 1024 + mo + m8] = v;
    }
  } else {
    const float* WB =
        isPe ? Wp_b : (nb < 512 ? Wu_b : (nb < 1024 ? Wq_b : Wkv_b));
    const int woff =
        isPe ? npbase : (nb < 512 ? nb : (nb < 1024 ? nb - 512 : nb - 1024));
    const bool rawDump = (!isPe && nb < 1024);
#pragma unroll
    for (int ct = 0; ct < 2; ++ct) {
      const int nl = wn + ct * 16 + ln;
      const float wb = WB[woff + nl];
#pragma unroll
      for (int rt = 0; rt < 4; ++rt)
#pragma unroll
        for (int r = 0; r < 4; ++r) {
          const int ml = wm + rt * 16 + quad * 4 + r;
          const float v = acc[rt][ct][r] + wb;
          sOut[ml * 72 + nl] = f2bf(rawDump ? v : fast_tanh(v));
        }
    }
    __syncthreads();
#pragma unroll
    for (int i = 0; i < 4; ++i) {
      const int idx = tid + i * 256;
      const int rr = idx >> 3, c8 = (idx & 7) * 8;
      const int m = mb + rr;
      const us8 v = *(const us8*)&sOut[rr * 72 + c8];
      if (isPe) {
        const int n = npbase + c8;
        const int h = n >> 6;
        *(us8*)&Kcomb[(size_t)m * 1024 + h * 128 + 64 + (n & 63)] = v;
      } else if (nb < 1024) {
        const int strm = nb >= 512 ? 1 : 0;
        const int n = (nb - strm * 512) + c8;
        const int h = n >> 6;
        const float* BC = strm ? Bfc : Buc;
        const float* BP = strm ? Bfp : Bup;
        float bcA[8], bpA[8];
        *(float4*)&bcA[0] = *(const float4*)&BC[n];
        *(float4*)&bcA[4] = *(const float4*)&BC[n + 4];
        *(float4*)&bpA[0] = *(const float4*)&BP[n];
        *(float4*)&bpA[4] = *(const float4*)&BP[n + 4];
        us8 oc, op;
#pragma unroll
        for (int jj = 0; jj < 8; ++jj) {
          const float vv = bf2f((unsigned short)v[jj]);
          oc[jj] = f2bf(fast_tanh(vv + bcA[jj]));
          op[jj] = f2bf(fast_tanh(vv + bpA[jj]));
        }
        *(us8*)&Qcomb[((size_t)strm * ROWS + m) * 1024 + h * 128 + (n & 63)] =
            oc;
        if (m != 0) {
          const int mp = (m < 1024) ? m - 1 : m;
          *(us8*)&Qcomb[((size_t)strm * ROWS + mp) * 1024 + h * 128 + 64 +
                        (n & 63)] = op;
        }
      } else {
        const int n = (nb - 1024) + c8;
        const int h = n >> 6;
        *(us8*)&Kcomb[(size_t)m * 1024 + h * 128 + (n & 63)] = v;
      }
    }
  }
}

// ============================================================
// attn: flash MFMA, static-max softmax, 768 blocks (3/CU):
//  bid<512: kt-HALF of a heavy unit (jt 8..15), writes bf16 numerator
//           partials (Opart slot half*4+t*2+b) + fp32 l partials.
//  bid>=512: single light unit (jt 0..7), writes normalized attO.
// Q fragments loaded directly from global (no sQ) -> 35.8 KB LDS.
// ============================================================
__global__ __launch_bounds__(256, 3) void attn_kernel(
    const ushort_t* __restrict__ Qcomb, const ushort_t* __restrict__ Kcomb,
    const ushort_t* __restrict__ vhT, ushort_t* __restrict__ attO,
    ushort_t* __restrict__ Opart, float* __restrict__ lpart) {
  const int bid = blockIdx.x;
  const int tid = threadIdx.x;
  const int w = tid >> 6, lane = tid & 63;
  const int ln = lane & 15, quad = lane >> 4;

  __shared__ __align__(16) ushort_t sK[64 * 136];
  __shared__ __align__(16) ushort_t sV[64 * 72];
  __shared__ __align__(16) ushort_t sP[64 * 72];

  int jt, kt0, kt1, half;
  bool isHalf;
  const int c = bid & 31;
  if (bid < 512) {
    isHalf = true;
    const int uu = bid >> 5;  // 0..15
    jt = 15 - (uu >> 1);
    half = uu & 1;
    const int h1 = (jt + 2) >> 1;
    kt0 = half ? h1 : 0;
    kt1 = half ? jt : (h1 - 1);
  } else {
    isHalf = false;
    half = 0;
    jt = 7 - ((bid - 512) >> 5);
    kt0 = 0;
    kt1 = jt;
  }
  const int t = c >> 4, b = (c >> 3) & 1, h = c & 7;

  // Q fragments: direct global loads (16B contiguous per lane)
  bhalf8 aq[4];
  {
    const size_t qbase =
        ((size_t)t * ROWS + b * SS + jt * 64 + w * 16 + ln) * 1024 + h * 128 +
        quad * 8;
#pragma unroll
    for (int kc = 0; kc < 4; ++kc)
      aq[kc] = *(const bhalf8*)&Qcomb[qbase + kc * 32];
  }

  // prefetch kt0
  uint4 pk[4], pv[2];
#pragma unroll
  for (int i = 0; i < 4; ++i) {
    const int idx = tid + i * 256;
    pk[i] = *(const uint4*)&Kcomb[((size_t)b * SS + kt0 * 64 + (idx >> 4)) *
                                      1024 + h * 128 + (idx & 15) * 8];
  }
#pragma unroll
  for (int i = 0; i < 2; ++i) {
    const int idx = tid + i * 256;
    pv[i] = *(const uint4*)&vhT[((size_t)b * 512 + h * 64 + (idx >> 3)) * 1024 +
                                kt0 * 64 + (idx & 7) * 8];
  }

  f32x4 oacc[4];
#pragma unroll
  for (int ct = 0; ct < 4; ++ct) oacc[ct] = (f32x4){0.f, 0.f, 0.f, 0.f};
  float lsum[4] = {0.f, 0.f, 0.f, 0.f};

  for (int kt = kt0; kt <= kt1; ++kt) {
    if (kt > kt0) __syncthreads();
#pragma unroll
    for (int i = 0; i < 4; ++i) {
      const int idx = tid + i * 256;
      *(uint4*)&sK[(idx >> 4) * 136 + (idx & 15) * 8] = pk[i];
    }
#pragma unroll
    for (int i = 0; i < 2; ++i) {
      const int idx = tid + i * 256;
      *(uint4*)&sV[(idx >> 3) * 72 + (idx & 7) * 8] = pv[i];
    }
    __syncthreads();
    if (kt < kt1) {
      const int k1 = (kt + 1) * 64;
#pragma unroll
      for (int i = 0; i < 4; ++i) {
        const int idx = tid + i * 256;
        pk[i] = *(const uint4*)&Kcomb[((size_t)b * SS + k1 + (idx >> 4)) *
                                          1024 + h * 128 + (idx & 15) * 8];
      }
#pragma unroll
      for (int i = 0; i < 2; ++i) {
        const int idx = tid + i * 256;
        pv[i] = *(const uint4*)&vhT[((size_t)b * 512 + h * 64 + (idx >> 3)) *
                                        1024 + k1 + (idx & 7) * 8];
      }
    }

    f32x4 sacc[4];
#pragma unroll
    for (int ct = 0; ct < 4; ++ct) {
      sacc[ct] = (f32x4){0.f, 0.f, 0.f, 0.f};
#pragma unroll
      for (int kc = 0; kc < 4; ++kc) {
        const bhalf8 bk =
            *(const bhalf8*)&sK[(ct * 16 + ln) * 136 + kc * 32 + quad * 8];
        sacc[ct] = __builtin_amdgcn_mfma_f32_16x16x32_bf16(aq[kc], bk,
                                                           sacc[ct], 0, 0, 0);
      }
    }

    const bool diag = (kt == jt);
#pragma unroll
    for (int ct = 0; ct < 4; ++ct)
#pragma unroll
      for (int r = 0; r < 4; ++r) {
        float p;
        if (diag && (ct * 16 + ln > w * 16 + quad * 4 + r))
          p = 0.f;
        else
          p = __expf(sacc[ct][r] * 0.125f - 16.f);
        sacc[ct][r] = p;
        lsum[r] += p;
      }

    // P -> LDS (truncating bf16 pack; p in [0,1], bias ~2^-9 harmless)
#pragma unroll
    for (int ct = 0; ct < 4; ++ct)
#pragma unroll
      for (int r = 0; r < 4; ++r)
        sP[(w * 16 + quad * 4 + r) * 72 + ct * 16 + ln] =
            (ushort_t)(__float_as_uint(sacc[ct][r]) >> 16);

#pragma unroll
    for (int kc = 0; kc < 2; ++kc) {
      const bhalf8 ap =
          *(const bhalf8*)&sP[(w * 16 + ln) * 72 + kc * 32 + quad * 8];
#pragma unroll
      for (int ct = 0; ct < 4; ++ct) {
        const bhalf8 bv =
            *(const bhalf8*)&sV[(ct * 16 + ln) * 72 + kc * 32 + quad * 8];
        oacc[ct] = __builtin_amdgcn_mfma_f32_16x16x32_bf16(ap, bv, oacc[ct],
                                                           0, 0, 0);
      }
    }
  }

  // epilogue
#pragma unroll
  for (int r = 0; r < 4; ++r) {
    float s = lsum[r];
    s += __shfl_xor(s, 1);
    s += __shfl_xor(s, 2);
    s += __shfl_xor(s, 4);
    s += __shfl_xor(s, 8);
    const int j = jt * 64 + w * 16 + quad * 4 + r;
    if (!isHalf) {
      const float inv = 1.f / s;
      const size_t orow = ((size_t)t * ROWS + b * SS + j) * 512 + h * 64;
#pragma unroll
      for (int ct = 0; ct < 4; ++ct)
        attO[orow + ct * 16 + ln] = f2bf(oacc[ct][r] * inv);
    } else {
      const int slot = half * 4 + t * 2 + b;
      const size_t prow = ((size_t)slot * 512 + (j - 512)) * 512 + h * 64;
#pragma unroll
      for (int ct = 0; ct < 4; ++ct)
        Opart[prow + ct * 16 + ln] = f2bf(oacc[ct][r]);
      if (ln == 0)
        lpart[((size_t)slot * 512 + (j - 512)) * 8 + h] = s;
    }
  }
}

// ============================================================
// ln: one wave per row (4 rows/block). j<512: attO (normalized bf16);
// j>=512: combine two bf16 numerator partials + fp32 l partials.
// ============================================================
__global__ __launch_bounds__(256) void ln_kernel(
    const float* __restrict__ u_emb, const float* __restrict__ f_emb,
    const ushort_t* __restrict__ attO, const ushort_t* __restrict__ Opart,
    const float* __restrict__ lpart, float* __restrict__ out) {
  const int rid = blockIdx.x * 4 + (threadIdx.x >> 6);
  const int lane = threadIdx.x & 63;
  const int t = rid >> 11, row = rid & 2047;
  const int b = row >> 10, j = row & 1023;
  const float* resid = t ? f_emb : u_emb;
  const size_t base = (size_t)row * 512;
  const size_t obase = ((size_t)t * ROWS + row) * 512;
  const int o = lane * 8;

  const float4 r0 = *(const float4*)&resid[base + o];
  const float4 r1 = *(const float4*)&resid[base + o + 4];
  float ra[8] = {r0.x, r0.y, r0.z, r0.w, r1.x, r1.y, r1.z, r1.w};
  float y[8];
  if (j < 512) {
    const us8 a = *(const us8*)&attO[obase + o];
#pragma unroll
    for (int i = 0; i < 8; ++i) y[i] = ra[i] + bf2f((unsigned short)a[i]);
  } else {
    const int h = lane >> 3;
    const int s0 = t * 2 + b, s1 = 4 + t * 2 + b;
    const size_t pr = (size_t)(j - 512);
    const float l = lpart[((size_t)s0 * 512 + pr) * 8 + h] +
                    lpart[((size_t)s1 * 512 + pr) * 8 + h];
    const float inv = 1.f / l;
    const us8 a0 = *(const us8*)&Opart[((size_t)s0 * 512 + pr) * 512 + o];
    const us8 a1 = *(const us8*)&Opart[((size_t)s1 * 512 + pr) * 512 + o];
#pragma unroll
    for (int i = 0; i < 8; ++i)
      y[i] = ra[i] + (bf2f((unsigned short)a0[i]) +
                      bf2f((unsigned short)a1[i])) * inv;
  }

  float s = 0.f, q = 0.f;
#pragma unroll
  for (int i = 0; i < 8; ++i) {
    s += y[i];
    q += y[i] * y[i];
  }
#pragma unroll
  for (int off = 1; off < 64; off <<= 1) {
    s += __shfl_xor(s, off);
    q += __shfl_xor(q, off);
  }
  const float mean = s * (1.f / 512.f);
  const float var = q * (1.f / 512.f) - mean * mean;
  const float rstd = rsqrtf(var + 1e-5f);

  float4 o0, o1;
  o0.x = (y[0] - mean) * rstd; o0.y = (y[1] - mean) * rstd;
  o0.z = (y[2] - mean) * rstd; o0.w = (y[3] - mean) * rstd;
  o1.x = (y[4] - mean) * rstd; o1.y = (y[5] - mean) * rstd;
  o1.z = (y[6] - mean) * rstd; o1.w = (y[7] - mean) * rstd;
  *(float4*)&out[obase + o] = o0;
  *(float4*)&out[obase + o + 4] = o1;
}

// ============================================================
extern "C" void kernel_launch(void* const* d_in, const int* in_sizes, int n_in,
                              void* d_out, int out_size, void* d_ws,
                              size_t ws_size, hipStream_t stream) {
  (void)in_sizes; (void)n_in; (void)out_size; (void)ws_size;
  const float* u_emb = (const float*)d_in[0];
  const float* f_emb = (const float*)d_in[1];
  const float* gpe = (const float*)d_in[2];
  const float* Wq_w = (const float*)d_in[5];
  const float* Wq_b = (const float*)d_in[6];
  const float* Wkv_w = (const float*)d_in[7];
  const float* Wkv_b = (const float*)d_in[8];
  const float* Wp_w = (const float*)d_in[9];
  const float* Wp_b = (const float*)d_in[10];
  const float* Wu_w = (const float*)d_in[11];
  const float* Wu_b = (const float*)d_in[12];
  const float* Bfc = (const float*)d_in[13];
  const float* Bfp = (const float*)d_in[14];
  const float* Buc = (const float*)d_in[15];
  const float* Bup = (const float*)d_in[16];
  float* out = (float*)d_out;

  ushort_t* ws = (ushort_t*)d_ws;
  const size_t SZ = (size_t)ROWS * EMB;  // 1048576
  ushort_t* Qcomb = ws;                  // 4*SZ
  ushort_t* Kcomb = ws + 4 * SZ;         // 2*SZ
  ushort_t* vhT = ws + 6 * SZ;           // SZ
  ushort_t* attO = ws + 7 * SZ;          // 2*SZ (bf16, normalized, j<512)
  ushort_t* Opart = ws + 9 * SZ;         // 2*SZ (bf16 numerators, 8 slots)
  float* lpart = (float*)(ws + 11 * SZ); // 32768 floats

  dim3 blk(256);
  hipLaunchKernelGGL(projpe_kernel, dim3(40, 16), blk, 0, stream, f_emb, gpe,
                     Wu_w, Wq_w, Wkv_w, Wp_w, Wu_b, Wq_b, Wkv_b, Wp_b, Buc,
                     Bup, Bfc, Bfp, Qcomb, Kcomb, vhT);
  hipLaunchKernelGGL(attn_kernel, dim3(768), blk, 0, stream, Qcomb, Kcomb, vhT,
                     attO, Opart, lpart);
  hipLaunchKernelGGL(ln_kernel, dim3(1024), blk, 0, stream, u_emb, f_emb, attO,
                     Opart, lpart, out);
}

// Round 9
// 158.189 us; speedup vs baseline: 1.0804x; 1.0804x over previous
//
#include <hip/hip_runtime.h>
#include <math.h>

#define EMB 512
#define NH 8
#define HD 64
#define BB 2
#define SS 1024
#define ROWS (BB * SS) /* 2048 */

typedef __attribute__((ext_vector_type(8))) short bhalf8;
typedef __attribute__((ext_vector_type(4))) float f32x4;
typedef __attribute__((ext_vector_type(8))) unsigned short us8;
typedef unsigned short ushort_t;

typedef const __attribute__((address_space(1))) void gas_void;
typedef __attribute__((address_space(3))) void las_void;

__device__ __forceinline__ void gl2lds16(const void* g, void* l) {
  __builtin_amdgcn_global_load_lds((gas_void*)g, (las_void*)l, 16, 0, 0);
}

__device__ __forceinline__ unsigned short f2bf(float x) {
  unsigned u = __float_as_uint(x);
  u = (u + 0x7FFFu + ((u >> 16) & 1u)) >> 16;
  return (unsigned short)u;
}
__device__ __forceinline__ float bf2f(unsigned short v) {
  return __uint_as_float(((unsigned)v) << 16);
}
__device__ __forceinline__ float fast_tanh(float x) {
  x = fminf(15.f, fmaxf(-15.f, x));
  const float e = __expf(2.f * x);
  return (e - 1.f) / (e + 1.f);
}

// ============================================================
// proj+pe MFMA GEMM (r7 structure) + zeroing of Onum/lpart.
// ============================================================
__global__ __launch_bounds__(256, 4) void projpe_kernel(
    const float* __restrict__ f_emb, const float* __restrict__ gpe,
    const float* __restrict__ Wu, const float* __restrict__ Wq,
    const float* __restrict__ Wkv, const float* __restrict__ Wp,
    const float* __restrict__ Wu_b, const float* __restrict__ Wq_b,
    const float* __restrict__ Wkv_b, const float* __restrict__ Wp_b,
    const float* __restrict__ Buc, const float* __restrict__ Bup,
    const float* __restrict__ Bfc, const float* __restrict__ Bfp,
    ushort_t* __restrict__ Qcomb, ushort_t* __restrict__ Kcomb,
    ushort_t* __restrict__ vhT, float* __restrict__ Onum,
    float* __restrict__ lpart) {
  const int bx = blockIdx.x;
  const int mb = blockIdx.y * 128;
  const int tid = threadIdx.x;
  const int w = tid >> 6, lane = tid & 63;
  const int ln = lane & 15, quad = lane >> 4;
  const int wm = (w >> 1) * 64, wn = (w & 1) * 32;

  __shared__ __align__(16) ushort_t sA[128 * 72];
  __shared__ __align__(16) ushort_t sB[64 * 72];

  // zero Onum (2M floats over blocks 0..511) and lpart (blocks 512..639)
  const int fb = blockIdx.y * 40 + bx;
  if (fb < 512) {
    const float4 z4 = {0.f, 0.f, 0.f, 0.f};
#pragma unroll
    for (int i = 0; i < 4; ++i)
      ((float4*)Onum)[(size_t)fb * 1024 + i * 256 + tid] = z4;
  } else {
    lpart[(fb - 512) * 256 + tid] = 0.f;
  }
  if (fb == 0) {  // zero Qcomb qp-half of row 1023 (no writer)
    const int t2 = tid >> 7, rem = tid & 127;
    const int h = rem >> 4, d4 = (rem & 15) * 4;
    *(ushort4*)&Qcomb[((size_t)t2 * ROWS + 1023) * 1024 + h * 128 + 64 + d4] =
        make_ushort4(0, 0, 0, 0);
  }

  const bool isPe = (bx >= 32);
  const int nb = isPe ? 0 : bx * 64;
  const int npbase = isPe ? (bx - 32) * 64 : 0;
  const float* Af = isPe ? gpe : f_emb;
  const int lda = isPe ? 128 : 512;
  const int trips = isPe ? 2 : 8;

  const float* Wsrc;
  int Nw, coff;
  if (isPe) { Wsrc = Wp; Nw = 512; coff = npbase; }
  else if (nb < 512) { Wsrc = Wu; Nw = 512; coff = nb; }
  else if (nb < 1024) { Wsrc = Wq; Nw = 512; coff = nb - 512; }
  else { Wsrc = Wkv; Nw = 1024; coff = nb - 1024; }

  const int bn = tid & 63;
  const int bk0 = (tid >> 6) * 16;

  f32x4 acc[4][2];
#pragma unroll
  for (int rt = 0; rt < 4; ++rt)
#pragma unroll
    for (int ct = 0; ct < 2; ++ct) acc[rt][ct] = (f32x4){0.f, 0.f, 0.f, 0.f};

  float4 qa[8];
  float qbw[16];
#pragma unroll
  for (int i = 0; i < 4; ++i) {
    const int idx = tid + i * 256;
    const size_t base = (size_t)(mb + (idx >> 3)) * lda + (idx & 7) * 8;
    qa[2 * i] = *(const float4*)&Af[base];
    qa[2 * i + 1] = *(const float4*)&Af[base + 4];
  }
#pragma unroll
  for (int j = 0; j < 16; ++j)
    qbw[j] = Wsrc[(size_t)(bk0 + j) * Nw + coff + bn];

  for (int t0 = 0; t0 < trips; ++t0) {
    __syncthreads();
#pragma unroll
    for (int i = 0; i < 4; ++i) {
      const int idx = tid + i * 256;
      us8 o;
      const float4 a = qa[2 * i], b = qa[2 * i + 1];
      o[0] = f2bf(a.x); o[1] = f2bf(a.y); o[2] = f2bf(a.z); o[3] = f2bf(a.w);
      o[4] = f2bf(b.x); o[5] = f2bf(b.y); o[6] = f2bf(b.z); o[7] = f2bf(b.w);
      *(us8*)&sA[(idx >> 3) * 72 + (idx & 7) * 8] = o;
    }
    {
      us8 o0, o1;
#pragma unroll
      for (int j = 0; j < 8; ++j) {
        o0[j] = f2bf(qbw[j]);
        o1[j] = f2bf(qbw[8 + j]);
      }
      *(us8*)&sB[bn * 72 + bk0] = o0;
      *(us8*)&sB[bn * 72 + bk0 + 8] = o1;
    }
    __syncthreads();
    if (t0 < trips - 1) {
      const int k1 = (t0 + 1) * 64;
#pragma unroll
      for (int i = 0; i < 4; ++i) {
        const int idx = tid + i * 256;
        const size_t base = (size_t)(mb + (idx >> 3)) * lda + k1 + (idx & 7) * 8;
        qa[2 * i] = *(const float4*)&Af[base];
        qa[2 * i + 1] = *(const float4*)&Af[base + 4];
      }
#pragma unroll
      for (int j = 0; j < 16; ++j)
        qbw[j] = Wsrc[(size_t)(k1 + bk0 + j) * Nw + coff + bn];
    }
#pragma unroll
    for (int kc = 0; kc < 2; ++kc) {
      bhalf8 af[4], bf_[2];
#pragma unroll
      for (int rt = 0; rt < 4; ++rt)
        af[rt] =
            *(const bhalf8*)&sA[(wm + rt * 16 + ln) * 72 + kc * 32 + quad * 8];
#pragma unroll
      for (int ct = 0; ct < 2; ++ct)
        bf_[ct] =
            *(const bhalf8*)&sB[(wn + ct * 16 + ln) * 72 + kc * 32 + quad * 8];
#pragma unroll
      for (int rt = 0; rt < 4; ++rt)
#pragma unroll
        for (int ct = 0; ct < 2; ++ct)
          acc[rt][ct] = __builtin_amdgcn_mfma_f32_16x16x32_bf16(
              af[rt], bf_[ct], acc[rt][ct], 0, 0, 0);
    }
  }

  __syncthreads();
  ushort_t* sOut = sA;

  if (!isPe && nb >= 1536) {
#pragma unroll
    for (int ct = 0; ct < 2; ++ct) {
      const int nl = wn + ct * 16 + ln;
      const float wb = Wkv_b[nb + nl - 1024];
#pragma unroll
      for (int rt = 0; rt < 4; ++rt)
#pragma unroll
        for (int r = 0; r < 4; ++r) {
          const int ml = wm + rt * 16 + quad * 4 + r;
          sOut[nl * 136 + ml] = f2bf(fast_tanh(acc[rt][ct][r] + wb));
        }
    }
    __syncthreads();
    const int b = mb >> 10, mo = mb & 1023;
#pragma unroll
    for (int i = 0; i < 4; ++i) {
      const int idx = tid + i * 256;
      const int nl = idx >> 4, m8 = (idx & 15) * 8;
      const us8 v = *(const us8*)&sOut[nl * 136 + m8];
      *(us8*)&vhT[((size_t)b * 512 + (nb - 1536) + nl) * 1024 + mo + m8] = v;
    }
  } else {
    const float* WB =
        isPe ? Wp_b : (nb < 512 ? Wu_b : (nb < 1024 ? Wq_b : Wkv_b));
    const int woff =
        isPe ? npbase : (nb < 512 ? nb : (nb < 1024 ? nb - 512 : nb - 1024));
    const bool rawDump = (!isPe && nb < 1024);
#pragma unroll
    for (int ct = 0; ct < 2; ++ct) {
      const int nl = wn + ct * 16 + ln;
      const float wb = WB[woff + nl];
#pragma unroll
      for (int rt = 0; rt < 4; ++rt)
#pragma unroll
        for (int r = 0; r < 4; ++r) {
          const int ml = wm + rt * 16 + quad * 4 + r;
          const float v = acc[rt][ct][r] + wb;
          sOut[ml * 72 + nl] = f2bf(rawDump ? v : fast_tanh(v));
        }
    }
    __syncthreads();
#pragma unroll
    for (int i = 0; i < 4; ++i) {
      const int idx = tid + i * 256;
      const int rr = idx >> 3, c8 = (idx & 7) * 8;
      const int m = mb + rr;
      const us8 v = *(const us8*)&sOut[rr * 72 + c8];
      if (isPe) {
        const int n = npbase + c8;
        const int h = n >> 6;
        *(us8*)&Kcomb[(size_t)m * 1024 + h * 128 + 64 + (n & 63)] = v;
      } else if (nb < 1024) {
        const int strm = nb >= 512 ? 1 : 0;
        const int n = (nb - strm * 512) + c8;
        const int h = n >> 6;
        const float* BC = strm ? Bfc : Buc;
        const float* BP = strm ? Bfp : Bup;
        float bcA[8], bpA[8];
        *(float4*)&bcA[0] = *(const float4*)&BC[n];
        *(float4*)&bcA[4] = *(const float4*)&BC[n + 4];
        *(float4*)&bpA[0] = *(const float4*)&BP[n];
        *(float4*)&bpA[4] = *(const float4*)&BP[n + 4];
        us8 oc, op;
#pragma unroll
        for (int jj = 0; jj < 8; ++jj) {
          const float vv = bf2f((unsigned short)v[jj]);
          oc[jj] = f2bf(fast_tanh(vv + bcA[jj]));
          op[jj] = f2bf(fast_tanh(vv + bpA[jj]));
        }
        *(us8*)&Qcomb[((size_t)strm * ROWS + m) * 1024 + h * 128 + (n & 63)] =
            oc;
        if (m != 0) {
          const int mp = (m < 1024) ? m - 1 : m;
          *(us8*)&Qcomb[((size_t)strm * ROWS + mp) * 1024 + h * 128 + 64 +
                        (n & 63)] = op;
        }
      } else {
        const int n = (nb - 1024) + c8;
        const int h = n >> 6;
        *(us8*)&Kcomb[(size_t)m * 1024 + h * 128 + (n & 63)] = v;
      }
    }
  }
}

// ============================================================
// attn: flash MFMA, static-max softmax. 512 uniform blocks, each
// handles 8-9 contiguous iters of the 4352-iter (combo x triangle)
// range. K/V staged via global_load_lds (16B DMA) into XOR-swizzled
// double-buffered LDS -> ONE barrier per iter, conflict-free reads.
// Partials accumulate into Onum/lpart via fp32 atomicAdd.
// ============================================================
__global__ __launch_bounds__(256, 2) void attn_kernel(
    const ushort_t* __restrict__ Qcomb, const ushort_t* __restrict__ Kcomb,
    const ushort_t* __restrict__ vhT, float* __restrict__ Onum,
    float* __restrict__ lpart) {
  const int bid = blockIdx.x;
  const int tid = threadIdx.x;
  const int w = tid >> 6, lane = tid & 63;
  const int ln = lane & 15, quad = lane >> 4;

  __shared__ __align__(16) ushort_t sK[2 * 64 * 128];  // 32 KB
  __shared__ __align__(16) ushort_t sV[2 * 64 * 64];   // 16 KB
  __shared__ __align__(16) ushort_t sP[64 * 72];       // 9 KB

  // global iter range
  const int G0 = (bid * 17) >> 1;
  const int G1 = ((bid + 1) * 17) >> 1;
  const int cnt = G1 - G0;

  int c = G0 / 136;
  int u = G0 - c * 136;
  int jt = (int)((sqrtf(8.f * u + 1.f) - 1.f) * 0.5f);
  while ((jt + 1) * (jt + 2) / 2 <= u) ++jt;
  while (jt * (jt + 1) / 2 > u) --jt;
  int kt = u - jt * (jt + 1) / 2;
  int t = c >> 4, b = (c >> 3) & 1, h = c & 7;

  // swizzled DMA staging of one K (64x128) + V (64x64) tile
  const int l4 = lane >> 4, p15 = lane & 15;
  const int l3 = lane >> 3, l7 = lane & 7;
#define STAGE_KV(B_, H_, KT_, BUF_)                                          \
  {                                                                          \
    const size_t kb_ = ((size_t)(B_)*SS + (KT_)*64) * 1024 + (H_)*128;       \
    ushort_t* bk_ = sK + (BUF_)*8192;                                        \
    _Pragma("unroll") for (int s_ = 0; s_ < 4; ++s_) {                       \
      const int q_ = w * 4 + s_;                                             \
      const int r_ = q_ * 4 + l4;                                            \
      const int gl_ = p15 ^ (r_ & 7);                                        \
      gl2lds16(&Kcomb[kb_ + (size_t)r_ * 1024 + gl_ * 8], &bk_[q_ * 512]);   \
    }                                                                        \
    const size_t vb_ = ((size_t)(B_)*512 + (H_)*64) * 1024 + (KT_)*64;       \
    ushort_t* bv_ = sV + (BUF_)*4096;                                        \
    _Pragma("unroll") for (int s_ = 0; s_ < 2; ++s_) {                       \
      const int q_ = w * 2 + s_;                                             \
      const int r_ = q_ * 8 + l3;                                            \
      const int gl_ = l7 ^ (r_ & 7);                                         \
      gl2lds16(&vhT[vb_ + (size_t)r_ * 1024 + gl_ * 8], &bv_[q_ * 512]);     \
    }                                                                        \
  }

  // Q fragments for (t,b,h,jt)
  bhalf8 aq[4];
#define LOAD_AQ(T_, B_, H_, JT_)                                             \
  {                                                                          \
    const size_t qb_ =                                                       \
        ((size_t)(T_)*ROWS + (B_)*SS + (JT_)*64 + w * 16 + ln) * 1024 +      \
        (H_)*128 + quad * 8;                                                 \
    _Pragma("unroll") for (int kc_ = 0; kc_ < 4; ++kc_) aq[kc_] =            \
        *(const bhalf8*)&Qcomb[qb_ + kc_ * 32];                              \
  }

  STAGE_KV(b, h, kt, 0);
  LOAD_AQ(t, b, h, jt);

  f32x4 oacc[4];
#pragma unroll
  for (int ct = 0; ct < 4; ++ct) oacc[ct] = (f32x4){0.f, 0.f, 0.f, 0.f};
  float lsum[4] = {0.f, 0.f, 0.f, 0.f};

  for (int it = 0; it < cnt; ++it) {
    __syncthreads();  // drains DMA for buffer (it&1); syncs block
    const ushort_t* bK = sK + (it & 1) * 8192;
    const ushort_t* bV = sV + (it & 1) * 4096;

    // next coords + DMA prefetch into other buffer
    int c2 = c, jt2 = jt, kt2 = kt + 1;
    if (kt2 > jt) {
      jt2 = jt + 1; kt2 = 0;
      if (jt2 > 15) { c2 = c + 1; jt2 = 0; }
    }
    if (it < cnt - 1) {
      const int b2 = (c2 >> 3) & 1, h2 = c2 & 7;
      STAGE_KV(b2, h2, kt2, ((it + 1) & 1));
    }

    // S = Q2 @ K2^T (swizzled reads)
    f32x4 sacc[4];
#pragma unroll
    for (int ct = 0; ct < 4; ++ct) {
      sacc[ct] = (f32x4){0.f, 0.f, 0.f, 0.f};
#pragma unroll
      for (int kc = 0; kc < 4; ++kc) {
        const bhalf8 bk = *(const bhalf8*)&bK[(ct * 16 + ln) * 128 +
                                             (((kc * 4 + quad) ^ l7) << 3)];
        sacc[ct] = __builtin_amdgcn_mfma_f32_16x16x32_bf16(aq[kc], bk,
                                                           sacc[ct], 0, 0, 0);
      }
    }

    const bool diag = (kt == jt);
#pragma unroll
    for (int ct = 0; ct < 4; ++ct)
#pragma unroll
      for (int r = 0; r < 4; ++r) {
        float p;
        if (diag && (ct * 16 + ln > w * 16 + quad * 4 + r))
          p = 0.f;
        else
          p = __expf(sacc[ct][r] * 0.125f - 16.f);
        sacc[ct][r] = p;
        lsum[r] += p;
      }

#pragma unroll
    for (int ct = 0; ct < 4; ++ct)
#pragma unroll
      for (int r = 0; r < 4; ++r)
        sP[(w * 16 + quad * 4 + r) * 72 + ct * 16 + ln] =
            (ushort_t)(__float_as_uint(sacc[ct][r]) >> 16);

#pragma unroll
    for (int kc = 0; kc < 2; ++kc) {
      const bhalf8 ap =
          *(const bhalf8*)&sP[(w * 16 + ln) * 72 + kc * 32 + quad * 8];
#pragma unroll
      for (int ct = 0; ct < 4; ++ct) {
        const bhalf8 bv = *(const bhalf8*)&bV[(ct * 16 + ln) * 64 +
                                             (((kc * 4 + quad) ^ l7) << 3)];
        oacc[ct] = __builtin_amdgcn_mfma_f32_16x16x32_bf16(ap, bv, oacc[ct],
                                                           0, 0, 0);
      }
    }

    // flush on row/combo change or end
    const bool rowEnd = (it == cnt - 1) || (jt2 != jt) || (c2 != c);
    if (rowEnd) {
#pragma unroll
      for (int r = 0; r < 4; ++r) {
        float s = lsum[r];
        s += __shfl_xor(s, 1);
        s += __shfl_xor(s, 2);
        s += __shfl_xor(s, 4);
        s += __shfl_xor(s, 8);
        const int j = jt * 64 + w * 16 + quad * 4 + r;
        if (ln == 0)
          atomicAdd(&lpart[((((t * 2 + b) << 10) + j) << 3) + h], s);
        const size_t orow = (((size_t)t * ROWS + b * SS + j) << 9) + h * 64;
#pragma unroll
        for (int ct = 0; ct < 4; ++ct)
          atomicAdd(&Onum[orow + ct * 16 + ln], oacc[ct][r]);
        lsum[r] = 0.f;
      }
#pragma unroll
      for (int ct = 0; ct < 4; ++ct) oacc[ct] = (f32x4){0.f, 0.f, 0.f, 0.f};
      if (it < cnt - 1) {
        const int t2 = c2 >> 4, b2 = (c2 >> 3) & 1, h2 = c2 & 7;
        LOAD_AQ(t2, b2, h2, jt2);
      }
    }
    c = c2; jt = jt2; kt = kt2;
    t = c >> 4; b = (c >> 3) & 1; h = c & 7;
  }
}

// ============================================================
// ln: y = resid + Onum/lpart, layernorm. One wave per row.
// ============================================================
__global__ __launch_bounds__(256) void ln_kernel(
    const float* __restrict__ u_emb, const float* __restrict__ f_emb,
    const float* __restrict__ Onum, const float* __restrict__ lpart,
    float* __restrict__ out) {
  const int rid = blockIdx.x * 4 + (threadIdx.x >> 6);
  const int lane = threadIdx.x & 63;
  const int t = rid >> 11, row = rid & 2047;
  const int b = row >> 10, j = row & 1023;
  const float* resid = t ? f_emb : u_emb;
  const size_t base = (size_t)row * 512;
  const size_t obase = ((size_t)t * ROWS + row) * 512;
  const int o = lane * 8;
  const int h = lane >> 3;
  const float inv = 1.f / lpart[((((t * 2 + b) << 10) + j) << 3) + h];

  const float4 n0 = *(const float4*)&Onum[obase + o];
  const float4 n1 = *(const float4*)&Onum[obase + o + 4];
  const float4 r0 = *(const float4*)&resid[base + o];
  const float4 r1 = *(const float4*)&resid[base + o + 4];
  float y[8];
  y[0] = r0.x + n0.x * inv; y[1] = r0.y + n0.y * inv;
  y[2] = r0.z + n0.z * inv; y[3] = r0.w + n0.w * inv;
  y[4] = r1.x + n1.x * inv; y[5] = r1.y + n1.y * inv;
  y[6] = r1.z + n1.z * inv; y[7] = r1.w + n1.w * inv;

  float s = 0.f, q = 0.f;
#pragma unroll
  for (int i = 0; i < 8; ++i) {
    s += y[i];
    q += y[i] * y[i];
  }
#pragma unroll
  for (int off = 1; off < 64; off <<= 1) {
    s += __shfl_xor(s, off);
    q += __shfl_xor(q, off);
  }
  const float mean = s * (1.f / 512.f);
  const float var = q * (1.f / 512.f) - mean * mean;
  const float rstd = rsqrtf(var + 1e-5f);

  float4 o0, o1;
  o0.x = (y[0] - mean) * rstd; o0.y = (y[1] - mean) * rstd;
  o0.z = (y[2] - mean) * rstd; o0.w = (y[3] - mean) * rstd;
  o1.x = (y[4] - mean) * rstd; o1.y = (y[5] - mean) * rstd;
  o1.z = (y[6] - mean) * rstd; o1.w = (y[7] - mean) * rstd;
  *(float4*)&out[obase + o] = o0;
  *(float4*)&out[obase + o + 4] = o1;
}

// ============================================================
extern "C" void kernel_launch(void* const* d_in, const int* in_sizes, int n_in,
                              void* d_out, int out_size, void* d_ws,
                              size_t ws_size, hipStream_t stream) {
  (void)in_sizes; (void)n_in; (void)out_size; (void)ws_size;
  const float* u_emb = (const float*)d_in[0];
  const float* f_emb = (const float*)d_in[1];
  const float* gpe = (const float*)d_in[2];
  const float* Wq_w = (const float*)d_in[5];
  const float* Wq_b = (const float*)d_in[6];
  const float* Wkv_w = (const float*)d_in[7];
  const float* Wkv_b = (const float*)d_in[8];
  const float* Wp_w = (const float*)d_in[9];
  const float* Wp_b = (const float*)d_in[10];
  const float* Wu_w = (const float*)d_in[11];
  const float* Wu_b = (const float*)d_in[12];
  const float* Bfc = (const float*)d_in[13];
  const float* Bfp = (const float*)d_in[14];
  const float* Buc = (const float*)d_in[15];
  const float* Bup = (const float*)d_in[16];
  float* out = (float*)d_out;

  ushort_t* ws = (ushort_t*)d_ws;
  const size_t SZ = (size_t)ROWS * EMB;  // 1048576
  ushort_t* Qcomb = ws;                  // 4*SZ
  ushort_t* Kcomb = ws + 4 * SZ;         // 2*SZ
  ushort_t* vhT = ws + 6 * SZ;           // SZ
  float* Onum = (float*)(ws + 7 * SZ);   // 2M floats (8 MB)
  float* lpart = (float*)(ws + 11 * SZ); // 32768 floats

  dim3 blk(256);
  hipLaunchKernelGGL(projpe_kernel, dim3(40, 16), blk, 0, stream, f_emb, gpe,
                     Wu_w, Wq_w, Wkv_w, Wp_w, Wu_b, Wq_b, Wkv_b, Wp_b, Buc,
                     Bup, Bfc, Bfp, Qcomb, Kcomb, vhT, Onum, lpart);
  hipLaunchKernelGGL(attn_kernel, dim3(512), blk, 0, stream, Qcomb, Kcomb, vhT,
                     Onum, lpart);
  hipLaunchKernelGGL(ln_kernel, dim3(1024), blk, 0, stream, u_emb, f_emb, Onum,
                     lpart, out);
}